// Round 17
// baseline (167.919 us; speedup 1.0000x reference)
//
#include <hip/hip_runtime.h>
#include <stdint.h>
#include <stddef.h>

#define Bb 128
#define Nn 512
#define Hh 128
#define ROWS (Bb*Nn)

typedef __bf16 bf16;
typedef __bf16 bf16x2 __attribute__((ext_vector_type(2)));
typedef __bf16 bf16x4 __attribute__((ext_vector_type(4)));
typedef __bf16 bf16x8 __attribute__((ext_vector_type(8)));
typedef float  f32x4  __attribute__((ext_vector_type(4)));

__device__ __forceinline__ void glds16(const void* g, void* l) {
  __builtin_amdgcn_global_load_lds(
      (const __attribute__((address_space(1))) void*)g,
      (__attribute__((address_space(3))) void*)l, 16, 0, 0);
}

// ============================ fragment-linear layouts ============================
// A 16(row)x32(k) bf16 MFMA subtile is stored as ONE 1KB block in lane order:
// lane l = g*16+l15 holds elements (row=l15, k=8g..8g+7) at block + l*16B.
// msgF[b]: block index kt*8 + mblk           (kt=j/32, mblk=channel/16)
// PF[b]:   block index it*16 + kt            (it=i/16,  kt=j/32)
// WuF[s]:  block index cblk*8 + kt (K=256)   WmF[s]: cblk*4 + kt (K=128)
// Consumers load block + lane*8 elements -> 64 lanes read contiguous 1KB.

// -------------------------------------------------- weight prep (all in one)
__global__ __launch_bounds__(256) void prep_all(
    const float* __restrict__ eW1, const float* __restrict__ Wm,
    const float* __restrict__ Wu, bf16* __restrict__ WTe,
    bf16* __restrict__ WmF, bf16* __restrict__ WuF) {
  int idx = blockIdx.x*256 + threadIdx.x;
  if (idx < 16384) {                       // eW1: 128x128 (old swizzled layout, LDS path)
    int k = idx >> 7, c = idx & 127;
    WTe[c*128 + (k ^ ((c & 7) << 3))] = (bf16)eW1[idx];
  } else if (idx < 65536) {                // Wm: 3x128x128 -> fragment-linear
    int sub = idx - 16384;
    int s = sub >> 14, r = sub & 16383;
    int k = r >> 7, c = r & 127;
    WmF[s*16384 + (((c>>4)*4 + (k>>5))*64 + ((k>>3)&3)*16 + (c&15))*8 + (k&7)] = (bf16)Wm[sub];
  } else if (idx < 65536 + 98304) {        // Wu: 3x256x128 -> fragment-linear
    int sub = idx - 65536;
    int s = sub >> 15, r = sub & 32767;
    int k = r >> 7, c = r & 127;
    WuF[s*32768 + (((c>>4)*8 + (k>>5))*64 + ((k>>3)&3)*16 + (c&15))*8 + (k&7)] = (bf16)Wu[sub];
  }
}

// -------------------------------------------------- fused embed L1+L2+msg0
// h = relu(relu(jets@W0+b0)@W1+b1); msg0 -> msgF fragment-linear.
__global__ __launch_bounds__(256) void embed_msg0(
    const float* __restrict__ jets, const float* __restrict__ W0,
    const float* __restrict__ b0, const bf16* __restrict__ WTe,
    const float* __restrict__ b1, const bf16* __restrict__ WmF0,
    const float* __restrict__ bm0, bf16* __restrict__ h,
    bf16* __restrict__ msgF) {
  __shared__ float sW0[8*128];
  __shared__ float sb0[128];
  __shared__ bf16 h0s[128*128];   // swizzled; reused for h-tile later
  __shared__ bf16 sWT[128*128];   // swizzled W1^T
  const int t = threadIdx.x;
  const int w = t >> 6, lane = t & 63, l15 = lane & 15, g = lane >> 4;
  const int row_blk = blockIdx.x*128;
  for (int q = w; q < 32; q += 4)
    glds16((const char*)WTe + q*1024 + lane*16, (char*)(void*)sWT + q*1024);
  for (int i = t; i < 8*128; i += 256) sW0[i] = W0[i];
  if (t < 128) sb0[t] = b0[t];
  __syncthreads();
  // layer 1: thread owns 1 row, 64 cols
  {
    const int row = t & 127, colbase = (t >> 7) * 64;
    const float4* jp = (const float4*)(jets + ((size_t)row_blk + row)*8);
    float4 x0 = jp[0], x1 = jp[1];
    float x[8] = {x0.x,x0.y,x0.z,x0.w,x1.x,x1.y,x1.z,x1.w};
    const int sw = (row & 7) << 3;
#pragma unroll
    for (int cg = 0; cg < 16; ++cg) {
      int c0 = colbase + cg*4;
      bf16x4 o;
#pragma unroll
      for (int j = 0; j < 4; ++j) {
        float a = sb0[c0+j];
#pragma unroll
        for (int f = 0; f < 8; ++f) a = fmaf(x[f], sW0[f*128 + c0 + j], a);
        o[j] = (bf16)fmaxf(a, 0.f);
      }
      *(bf16x4*)(h0s + row*128 + (c0 ^ sw)) = o;
    }
  }
  __syncthreads();
  // layer 2: MFMA, 4 waves 2x2
  const int wr = (w & 1)*64, wc = (w >> 1)*64;
  f32x4 acc[4][4];
#pragma unroll
  for (int m = 0; m < 4; ++m)
#pragma unroll
    for (int n = 0; n < 4; ++n) acc[m][n] = (f32x4){0.f,0.f,0.f,0.f};
#pragma unroll
  for (int kk = 0; kk < 128; kk += 32) {
    bf16x8 bfr[4], wfr[4];
#pragma unroll
    for (int n = 0; n < 4; ++n) {
      int row = wr + n*16 + l15;
      bfr[n] = *(const bf16x8*)(h0s + row*128 + ((kk + 8*g) ^ ((row & 7) << 3)));
    }
#pragma unroll
    for (int m = 0; m < 4; ++m) {
      int c = wc + m*16 + l15;
      wfr[m] = *(const bf16x8*)(sWT + c*128 + ((kk + 8*g) ^ ((c & 7) << 3)));
    }
#pragma unroll
    for (int m = 0; m < 4; ++m)
#pragma unroll
      for (int n = 0; n < 4; ++n)
        acc[m][n] = __builtin_amdgcn_mfma_f32_16x16x32_bf16(wfr[m], bfr[n], acc[m][n], 0,0,0);
  }
  __syncthreads();   // everyone done reading h0s before overwrite
#pragma unroll
  for (int m = 0; m < 4; ++m) {
    f32x4 bs = *(const f32x4*)(b1 + wc + m*16 + g*4);
#pragma unroll
    for (int n = 0; n < 4; ++n) {
      int lr = wr + n*16 + l15;
      int r = row_blk + lr;
      int c0 = wc + m*16 + g*4;
      bf16x4 o;
#pragma unroll
      for (int j = 0; j < 4; ++j) o[j] = (bf16)fmaxf(acc[m][n][j] + bs[j], 0.f);
      *(bf16x4*)(h + (size_t)r*128 + c0) = o;
      *(bf16x4*)(h0s + lr*128 + (c0 ^ ((lr & 7) << 3))) = o;
    }
  }
  __syncthreads();
  // msg0: relu(htile @ Wm0 + bm0) -> msgF fragment-linear blocks
  {
    f32x4 acc2[4][4];
#pragma unroll
    for (int m = 0; m < 4; ++m)
#pragma unroll
      for (int n = 0; n < 4; ++n) acc2[m][n] = (f32x4){0.f,0.f,0.f,0.f};
#pragma unroll
    for (int kk = 0; kk < 128; kk += 32) {
      bf16x8 bfr[4], wfr[4];
#pragma unroll
      for (int n = 0; n < 4; ++n) {
        int lr = wr + n*16 + l15;
        bfr[n] = *(const bf16x8*)(h0s + lr*128 + ((kk + 8*g) ^ ((lr & 7) << 3)));
      }
#pragma unroll
      for (int m = 0; m < 4; ++m) {
        int cblk = (wc >> 4) + m;
        wfr[m] = *(const bf16x8*)(WmF0 + (size_t)(cblk*4 + (kk >> 5))*512 + lane*8);
      }
#pragma unroll
      for (int m = 0; m < 4; ++m)
#pragma unroll
        for (int n = 0; n < 4; ++n)
          acc2[m][n] = __builtin_amdgcn_mfma_f32_16x16x32_bf16(bfr[n], wfr[m], acc2[m][n], 0,0,0);
    }
    const int b = row_blk >> 9;
    const int rbase = (row_blk & 511) + wr;
#pragma unroll
    for (int m = 0; m < 4; ++m) {
      int c = wc + m*16 + l15;
      int mblk = (wc >> 4) + m;
      float bc = bm0[c];
#pragma unroll
      for (int n = 0; n < 4; ++n) {
        int rl = rbase + n*16 + g*4;
        bf16x4 o;
#pragma unroll
        for (int j = 0; j < 4; ++j) o[j] = (bf16)fmaxf(acc2[m][n][j] + bc, 0.f);
        size_t off = (size_t)b*65536 + (size_t)((rl>>5)*8 + mblk)*512
                   + (((rl>>3)&3)*16 + l15)*8 + (rl&7);
        *(bf16x4*)(msgF + off) = o;
      }
    }
  }
}

// -------------------------------------------------- fused per-iteration kernel
// COMPUTE_P (iter 0): Phase A recomputes E in-register (bit-identical FP order
// to the old pmat), feeds MFMA directly, AND stores fragment-linear PF + rsum
// for iters 1-2 -- the separate pmat pass is gone. Xs/cbs overlay the htile
// LDS region (dead until Phase B epilogue; two barriers in between).
// !COMPUTE_P: Phase A is the R16 pipelined pure GEMM on PF (coalesced,
// 2-deep double-buffered; __launch_bounds__(256,1) keeps the VGPR budget open).
// Phase B: h_new = relu([h|agg]@Wu+bu)*mask (in-place h); WuF coalesced.
// Phase C (DO_MSG): msgFout = relu(h_new@Wm+bm)^T (fragment-linear out).
template<bool COMPUTE_P, bool DO_MSG>
__global__ __launch_bounds__(256, 1) void iter_fused(
    const float* __restrict__ jets, bf16* __restrict__ PF,
    float* __restrict__ rsum,
    const float* __restrict__ mask, const bf16* __restrict__ msgFin,
    bf16* __restrict__ h,
    const bf16* __restrict__ WuF, const float* __restrict__ bu,
    const bf16* __restrict__ WmF, const float* __restrict__ bm,
    bf16* __restrict__ msgFout) {
  __shared__ __align__(16) char smem[65536];
  bf16* htile = (bf16*)smem;                 // [128][128] 32KB (phase B/C)
  bf16* aggs  = (bf16*)(smem + 32768);       // [128][128] 32KB
  float* Xs   = (float*)smem;                // [512*9] 18KB (COMPUTE_P phase A)
  float* cbs  = (float*)(smem + 18432);      // [512]    2KB (COMPUTE_P phase A)
  const int t = threadIdx.x;
  const int b  = blockIdx.x & 127;
  const int ic = blockIdx.x >> 7;             // 0..3
  const int i0 = ic*128;
  const int w = t >> 6, lane = t & 63, l15 = lane & 15, g = lane >> 4;

  if (COMPUTE_P) {
    const float* jb = jets + (size_t)b*Nn*8;
    for (int j = t; j < Nn; j += 256) {
      float s2 = 0.f;
#pragma unroll
      for (int f = 0; f < 8; ++f) { float v = jb[j*8+f]; Xs[j*9+f] = v; s2 = fmaf(v,v,s2); }
      cbs[j] = s2 + (mask[(size_t)b*Nn+j] > 0.f ? 0.f : 1e9f);
    }
    __syncthreads();
  }

  // ================= Phase A: agg rows i0 + w*32 .. +31
  {
    const int i0w = i0 + w*32;
    float r_i[2], lsum[2] = {0.f, 0.f};
    float xi2[2][8], sqi[2];
    if (COMPUTE_P) {
#pragma unroll
      for (int r = 0; r < 2; ++r) {
        int i = i0w + r*16 + l15;
        float sq = 0.f;
#pragma unroll
        for (int f = 0; f < 8; ++f) {
          float v = Xs[i*9+f];
          xi2[r][f] = 2.f*v;
          sq = fmaf(v, v, sq);
        }
        sqi[r] = sq;
      }
    } else {
#pragma unroll
      for (int r = 0; r < 2; ++r) r_i[r] = rsum[(size_t)b*Nn + i0w + r*16 + l15];
    }
    f32x4 acc[2][8];
#pragma unroll
    for (int r = 0; r < 2; ++r)
#pragma unroll
      for (int m = 0; m < 8; ++m) acc[r][m] = (f32x4){0.f,0.f,0.f,0.f};
    const bf16* mBF = msgFin + (size_t)b*65536 + lane*8;
    bf16* pBF = PF + ((size_t)b*32 + (i0w >> 4))*16*512 + lane*8;

    bf16x8 afrA[8], afrB[8], pfrA[2], pfrB[2];
    auto loadAfrA = [&](int kt) {
#pragma unroll
      for (int m = 0; m < 8; ++m) afrA[m] = *(const bf16x8*)(mBF + (kt*8 + m)*512);
    };
    auto loadAfrB = [&](int kt) {
#pragma unroll
      for (int m = 0; m < 8; ++m) afrB[m] = *(const bf16x8*)(mBF + (kt*8 + m)*512);
    };
    auto loadPfrA = [&](int kt) {
      pfrA[0] = *(const bf16x8*)(pBF + kt*512);
      pfrA[1] = *(const bf16x8*)(pBF + (16 + kt)*512);
    };
    auto loadPfrB = [&](int kt) {
      pfrB[0] = *(const bf16x8*)(pBF + kt*512);
      pfrB[1] = *(const bf16x8*)(pBF + (16 + kt)*512);
    };
    auto makeP = [&](int kt, bf16x8* pfr) {   // bit-identical to old pmat loop
      int j0 = kt*32;
#pragma unroll
      for (int e = 0; e < 8; ++e) {
        int j = j0 + 8*g + e;
        float xj[8];
#pragma unroll
        for (int f = 0; f < 8; ++f) xj[f] = Xs[j*9+f];
        float cb = cbs[j];
        float d0 = -(cb + sqi[0]);
        float d1 = -(cb + sqi[1]);
#pragma unroll
        for (int f = 0; f < 8; ++f) {
          d0 = fmaf(xi2[0][f], xj[f], d0);
          d1 = fmaf(xi2[1][f], xj[f], d1);
        }
        float ev0 = __expf(d0), ev1 = __expf(d1);
        lsum[0] += ev0; lsum[1] += ev1;
        pfr[0][e] = (bf16)ev0;
        pfr[1][e] = (bf16)ev1;
      }
      *(bf16x8*)(pBF + kt*512)        = pfr[0];   // store for iters 1-2
      *(bf16x8*)(pBF + (16 + kt)*512) = pfr[1];
    };
    auto compute = [&](const bf16x8* afr, const bf16x8* pfr) {
#pragma unroll
      for (int m = 0; m < 8; ++m) {
        acc[0][m] = __builtin_amdgcn_mfma_f32_16x16x32_bf16(afr[m], pfr[0], acc[0][m], 0,0,0);
        acc[1][m] = __builtin_amdgcn_mfma_f32_16x16x32_bf16(afr[m], pfr[1], acc[1][m], 0,0,0);
      }
    };

    loadAfrA(0);
    if (!COMPUTE_P) loadPfrA(0);
#pragma unroll
    for (int kt = 0; kt < 16; kt += 2) {
      loadAfrB(kt + 1);
      if (COMPUTE_P) makeP(kt, pfrA); else loadPfrB(kt + 1);
      compute(afrA, pfrA);
      if (kt + 2 < 16) loadAfrA(kt + 2);
      if (COMPUTE_P) makeP(kt + 1, pfrB);
      else if (kt + 2 < 16) loadPfrA(kt + 2);
      compute(afrB, pfrB);
    }
    if (COMPUTE_P) {
#pragma unroll
      for (int r = 0; r < 2; ++r) {
        float s = lsum[r];
        s += __shfl_xor(s, 16, 64);
        s += __shfl_xor(s, 32, 64);
        r_i[r] = 1.f/s;
        if (g == 0) rsum[(size_t)b*Nn + i0w + r*16 + l15] = r_i[r];
      }
    }
    // epilogue -> aggs LDS (swizzled), normalized by r_i
#pragma unroll
    for (int r = 0; r < 2; ++r) {
      int lr = w*32 + r*16 + l15;      // local row 0..127
#pragma unroll
      for (int m = 0; m < 8; ++m) {
        bf16x4 o;
#pragma unroll
        for (int j = 0; j < 4; ++j) o[j] = (bf16)(acc[r][m][j] * r_i[r]);
        int c0 = m*16 + g*4;
        *(bf16x4*)(aggs + lr*128 + (c0 ^ ((lr & 7) << 3))) = o;
      }
    }
  }
  __syncthreads();   // aggs visible; Xs dead (htile overlay safe after next barrier)

  // ================= Phase B: h_new = relu([h|agg] @ Wu + bu) * mask
  const int wr = (w & 1)*64, wc = (w >> 1)*64;
  const size_t growbase = (size_t)b*Nn + i0;
  {
    f32x4 acc[4][4];
#pragma unroll
    for (int m = 0; m < 4; ++m)
#pragma unroll
      for (int n = 0; n < 4; ++n) acc[m][n] = (f32x4){0.f,0.f,0.f,0.f};
#pragma unroll
    for (int kk = 0; kk < 256; kk += 32) {
      bf16x8 bfr[4];
      if (kk < 128) {
#pragma unroll
        for (int n = 0; n < 4; ++n)
          bfr[n] = *(const bf16x8*)(h + (growbase + wr + n*16 + l15)*128 + kk + 8*g);
      } else {
#pragma unroll
        for (int n = 0; n < 4; ++n) {
          int lr = wr + n*16 + l15;
          int kl = (kk - 128) + 8*g;
          bfr[n] = *(const bf16x8*)(aggs + lr*128 + (kl ^ ((lr & 7) << 3)));
        }
      }
      bf16x8 wfr[4];
#pragma unroll
      for (int m = 0; m < 4; ++m) {
        int cblk = (wc >> 4) + m;
        wfr[m] = *(const bf16x8*)(WuF + (size_t)(cblk*8 + (kk >> 5))*512 + lane*8);
      }
#pragma unroll
      for (int m = 0; m < 4; ++m)
#pragma unroll
        for (int n = 0; n < 4; ++n)
          acc[m][n] = __builtin_amdgcn_mfma_f32_16x16x32_bf16(wfr[m], bfr[n], acc[m][n], 0,0,0);
    }
    __syncthreads();  // all h reads (cross-wave cols) + aggs reads drained
#pragma unroll
    for (int m = 0; m < 4; ++m) {
      f32x4 bs = *(const f32x4*)(bu + wc + m*16 + g*4);
#pragma unroll
      for (int n = 0; n < 4; ++n) {
        int lr = wr + n*16 + l15;
        size_t r = growbase + lr;
        float mv = mask[r];
        bf16x4 o;
#pragma unroll
        for (int j = 0; j < 4; ++j)
          o[j] = (bf16)(fmaxf(acc[m][n][j] + bs[j], 0.f) * mv);
        int c0 = wc + m*16 + g*4;
        *(bf16x4*)(h + r*128 + c0) = o;
        if (DO_MSG)
          *(bf16x4*)(htile + lr*128 + (c0 ^ ((lr & 7) << 3))) = o;
      }
    }
  }
  if (!DO_MSG) return;
  __syncthreads();   // htile visible

  // ================= Phase C: msgFout = relu(h_new @ Wm + bm)^T (frag-linear)
  {
    f32x4 acc[4][4];
#pragma unroll
    for (int m = 0; m < 4; ++m)
#pragma unroll
      for (int n = 0; n < 4; ++n) acc[m][n] = (f32x4){0.f,0.f,0.f,0.f};
#pragma unroll
    for (int kk = 0; kk < 128; kk += 32) {
      bf16x8 bfr[4], wfr[4];
#pragma unroll
      for (int n = 0; n < 4; ++n) {
        int lr = wr + n*16 + l15;
        bfr[n] = *(const bf16x8*)(htile + lr*128 + ((kk + 8*g) ^ ((lr & 7) << 3)));
      }
#pragma unroll
      for (int m = 0; m < 4; ++m) {
        int cblk = (wc >> 4) + m;
        wfr[m] = *(const bf16x8*)(WmF + (size_t)(cblk*4 + (kk >> 5))*512 + lane*8);
      }
#pragma unroll
      for (int m = 0; m < 4; ++m)
#pragma unroll
        for (int n = 0; n < 4; ++n)
          acc[m][n] = __builtin_amdgcn_mfma_f32_16x16x32_bf16(bfr[n], wfr[m], acc[m][n], 0,0,0);
    }
#pragma unroll
    for (int m = 0; m < 4; ++m) {
      int c = wc + m*16 + l15;
      int mblk = (wc >> 4) + m;
      float bc = bm[c];
#pragma unroll
      for (int n = 0; n < 4; ++n) {
        int rl = i0 + wr + n*16 + g*4;
        bf16x4 o;
#pragma unroll
        for (int j = 0; j < 4; ++j) o[j] = (bf16)fmaxf(acc[m][n][j] + bc, 0.f);
        size_t off = (size_t)b*65536 + (size_t)((rl>>5)*8 + mblk)*512
                   + (((rl>>3)&3)*16 + l15)*8 + (rl&7);
        *(bf16x4*)(msgFout + off) = o;
      }
    }
  }
}

// -------------------------------------------------- fused pool + readout
__global__ __launch_bounds__(256) void pool_readout(
    const bf16* __restrict__ h, const float* __restrict__ mask,
    const float* __restrict__ W1, const float* __restrict__ b1,
    const float* __restrict__ W2, const float* __restrict__ b2,
    float* __restrict__ out) {
  __shared__ float part[3][128];
  __shared__ float pl[128];
  __shared__ float hid[128];
  int b = blockIdx.x, t = threadIdx.x, g = t >> 6, cp = (t & 63)*2;
  float a0 = 0.f, a1 = 0.f;
  for (int n = g*128; n < g*128+128; ++n) {
    float mv = mask[(size_t)b*Nn + n];
    bf16x2 v = *(const bf16x2*)(h + ((size_t)b*Nn + n)*128 + cp);
    a0 = fmaf((float)v[0], mv, a0);
    a1 = fmaf((float)v[1], mv, a1);
  }
  if (g > 0) { part[g-1][cp] = a0; part[g-1][cp+1] = a1; }
  __syncthreads();
  if (g == 0) {
    pl[cp]   = a0 + part[0][cp]   + part[1][cp]   + part[2][cp];
    pl[cp+1] = a1 + part[0][cp+1] + part[1][cp+1] + part[2][cp+1];
  }
  __syncthreads();
  if (t < 128) {
    float a = b1[t];
#pragma unroll 4
    for (int j = 0; j < 128; ++j) a = fmaf(pl[j], W1[j*128 + t], a);
    hid[t] = fmaxf(a, 0.f);
  }
  __syncthreads();
  if (t < 128) {
    float a = b2[t];
#pragma unroll 4
    for (int j = 0; j < 128; ++j) a = fmaf(hid[j], W2[j*128 + t], a);
    out[(size_t)b*128 + t] = a;
  }
}

// -------------------------------------------------- launch
extern "C" void kernel_launch(void* const* d_in, const int* in_sizes, int n_in,
                              void* d_out, int out_size, void* d_ws, size_t ws_size,
                              hipStream_t stream) {
  const float* jets = (const float*)d_in[0];
  const float* mask = (const float*)d_in[1];
  const float* eW0  = (const float*)d_in[2];
  const float* eb0  = (const float*)d_in[3];
  const float* eW1  = (const float*)d_in[4];
  const float* eb1  = (const float*)d_in[5];
  const float* Wm   = (const float*)d_in[6];
  const float* bm   = (const float*)d_in[7];
  const float* Wu   = (const float*)d_in[8];
  const float* bu   = (const float*)d_in[9];
  const float* rW1  = (const float*)d_in[10];
  const float* rb1  = (const float*)d_in[11];
  const float* rW2  = (const float*)d_in[12];
  const float* rb2  = (const float*)d_in[13];
  float* out = (float*)d_out;

  bf16* h     = (bf16*)d_ws;                    // ROWS*128
  bf16* msgFA = h     + (size_t)ROWS*128;       // ROWS*128 (fragment-linear)
  bf16* msgFB = msgFA + (size_t)ROWS*128;       // ROWS*128 (ping-pong)
  bf16* PF    = msgFB + (size_t)ROWS*128;       // Bb*512*512 (67 MB, frag-linear E)
  bf16* WTe   = PF    + (size_t)Bb*512*512;     // 128*128 (old layout)
  bf16* WmF   = WTe   + 128*128;                // 3*128*128 (frag-linear)
  bf16* WuF   = WmF   + 3*128*128;              // 3*256*128 (frag-linear)
  float* rsum = (float*)(WuF + 3*256*128);      // ROWS (1/l_i)

  prep_all<<<640, 256, 0, stream>>>(eW1, Wm, Wu, WTe, WmF, WuF);
  embed_msg0<<<ROWS/128, 256, 0, stream>>>(jets, eW0, eb0, WTe, eb1,
                                           WmF, bm, h, msgFA);
  // iter 0 (computes + stores PF/rsum on the fly): msgFA -> msgFB
  iter_fused<true,true><<<Bb*4, 256, 0, stream>>>(
      jets, PF, rsum, mask, msgFA, h,
      WuF, bu, WmF + (size_t)1*128*128, bm + 1*128, msgFB);
  // iter 1: msgFB -> msgFA
  iter_fused<false,true><<<Bb*4, 256, 0, stream>>>(
      jets, PF, rsum, mask, msgFB, h,
      WuF + (size_t)1*256*128, bu + 1*128,
      WmF + (size_t)2*128*128, bm + 2*128, msgFA);
  // iter 2 (no next msg): reads msgFA
  iter_fused<false,false><<<Bb*4, 256, 0, stream>>>(
      jets, PF, rsum, mask, msgFA, h,
      WuF + (size_t)2*256*128, bu + 2*128, nullptr, nullptr, nullptr);

  pool_readout<<<Bb, 256, 0, stream>>>(h, mask, rW1, rb1, rW2, rb2, out);
}

// Round 18
// 159.126 us; speedup vs baseline: 1.0553x; 1.0553x over previous
//
#include <hip/hip_runtime.h>
#include <stdint.h>
#include <stddef.h>

#define Bb 128
#define Nn 512
#define Hh 128
#define ROWS (Bb*Nn)

typedef __bf16 bf16;
typedef __bf16 bf16x2 __attribute__((ext_vector_type(2)));
typedef __bf16 bf16x4 __attribute__((ext_vector_type(4)));
typedef __bf16 bf16x8 __attribute__((ext_vector_type(8)));
typedef float  f32x4  __attribute__((ext_vector_type(4)));

__device__ __forceinline__ void glds16(const void* g, void* l) {
  __builtin_amdgcn_global_load_lds(
      (const __attribute__((address_space(1))) void*)g,
      (__attribute__((address_space(3))) void*)l, 16, 0, 0);
}

// ============================ fragment-linear layouts ============================
// A 16(row)x32(k) bf16 MFMA subtile is stored as ONE 1KB block in lane order:
// lane l = g*16+l15 holds elements (row=l15, k=8g..8g+7) at block + l*16B.
// msgF[b]: block index kt*8 + mblk           (kt=j/32, mblk=channel/16)
// PF[b]:   block index it*16 + kt            (it=i/16,  kt=j/32)
// WuF[s]:  block index cblk*8 + kt (K=256)   WmF[s]: cblk*4 + kt (K=128)
// Consumers load block + lane*8 elements -> 64 lanes read contiguous 1KB.

// -------------------------------------------------- prep + pmat (one dispatch)
// blocks 0..511:   pmat -- E_ij = exp(2 x_i.x_j - |x_j|^2 - pen_j - |x_i|^2)
//                  UNNORMALIZED -> PF (frag-linear, coalesced); rsum = 1/sum E.
// blocks 512..1151: weight prep (WTe swizzled; WmF/WuF frag-linear).
// The two halves are independent and run concurrently in one dispatch.
__global__ __launch_bounds__(256) void prep_pmat(
    const float* __restrict__ eW1, const float* __restrict__ Wm,
    const float* __restrict__ Wu, bf16* __restrict__ WTe,
    bf16* __restrict__ WmF, bf16* __restrict__ WuF,
    const float* __restrict__ jets, const float* __restrict__ mask,
    bf16* __restrict__ PF, float* __restrict__ rsum) {
  __shared__ float Xs[Nn*9];
  __shared__ float cbs[Nn];
  const int t = threadIdx.x;
  if (blockIdx.x >= 512) {               // ---- weight prep half
    int idx = (blockIdx.x - 512)*256 + t;
    if (idx < 16384) {                       // eW1: 128x128 (swizzled, LDS path)
      int k = idx >> 7, c = idx & 127;
      WTe[c*128 + (k ^ ((c & 7) << 3))] = (bf16)eW1[idx];
    } else if (idx < 65536) {                // Wm: 3x128x128 -> fragment-linear
      int sub = idx - 16384;
      int s = sub >> 14, r = sub & 16383;
      int k = r >> 7, c = r & 127;
      WmF[s*16384 + (((c>>4)*4 + (k>>5))*64 + ((k>>3)&3)*16 + (c&15))*8 + (k&7)] = (bf16)Wm[sub];
    } else {                                 // Wu: 3x256x128 -> fragment-linear
      int sub = idx - 65536;
      int s = sub >> 15, r = sub & 32767;
      int k = r >> 7, c = r & 127;
      WuF[s*32768 + (((c>>4)*8 + (k>>5))*64 + ((k>>3)&3)*16 + (c&15))*8 + (k&7)] = (bf16)Wu[sub];
    }
    return;
  }
  // ---- pmat half (b = wgid&127 keeps XCD mapping identical to iter_fused)
  const int b = blockIdx.x & 127, ic = blockIdx.x >> 7;
  const int i0 = ic*128;
  const float* jb = jets + (size_t)b*Nn*8;
  for (int j = t; j < Nn; j += 256) {
    float s2 = 0.f;
#pragma unroll
    for (int f = 0; f < 8; ++f) { float v = jb[j*8+f]; Xs[j*9+f] = v; s2 = fmaf(v,v,s2); }
    cbs[j] = s2 + (mask[(size_t)b*Nn+j] > 0.f ? 0.f : 1e9f);
  }
  __syncthreads();
  const int w = t >> 6, lane = t & 63, l15 = lane & 15, g = lane >> 4;
  const int i0w = i0 + w*32;
  float xi2[2][8], sqi[2], lsum[2];
#pragma unroll
  for (int r = 0; r < 2; ++r) {
    int i = i0w + r*16 + l15;
    float sq = 0.f;
#pragma unroll
    for (int f = 0; f < 8; ++f) {
      float v = Xs[i*9+f];
      xi2[r][f] = 2.f*v;
      sq = fmaf(v, v, sq);
    }
    sqi[r] = sq;
    lsum[r] = 0.f;
  }
  bf16* Pr[2];
#pragma unroll
  for (int r = 0; r < 2; ++r) {
    int it = (i0w >> 4) + r;
    Pr[r] = PF + (((size_t)b*32 + it)*16)*512 + lane*8;
  }
#pragma unroll 2
  for (int j0 = 0; j0 < Nn; j0 += 32) {
    bf16x8 pfr[2];
#pragma unroll
    for (int e = 0; e < 8; ++e) {
      int j = j0 + 8*g + e;
      float xj[8];
#pragma unroll
      for (int f = 0; f < 8; ++f) xj[f] = Xs[j*9+f];
      float cb = cbs[j];
      float d0 = -(cb + sqi[0]);
      float d1 = -(cb + sqi[1]);
#pragma unroll
      for (int f = 0; f < 8; ++f) {
        d0 = fmaf(xi2[0][f], xj[f], d0);
        d1 = fmaf(xi2[1][f], xj[f], d1);
      }
      float ev0 = __expf(d0), ev1 = __expf(d1);
      lsum[0] += ev0; lsum[1] += ev1;
      pfr[0][e] = (bf16)ev0;
      pfr[1][e] = (bf16)ev1;
    }
#pragma unroll
    for (int r = 0; r < 2; ++r)
      *(bf16x8*)(Pr[r] + (j0 >> 5)*512) = pfr[r];
  }
#pragma unroll
  for (int r = 0; r < 2; ++r) {
    float s = lsum[r];
    s += __shfl_xor(s, 16, 64);
    s += __shfl_xor(s, 32, 64);
    if (g == 0) rsum[(size_t)b*Nn + i0w + r*16 + l15] = 1.f/s;
  }
}

// -------------------------------------------------- fused embed L1+L2+msg0
// h = relu(relu(jets@W0+b0)@W1+b1); msg0 -> msgF fragment-linear.
__global__ __launch_bounds__(256) void embed_msg0(
    const float* __restrict__ jets, const float* __restrict__ W0,
    const float* __restrict__ b0, const bf16* __restrict__ WTe,
    const float* __restrict__ b1, const bf16* __restrict__ WmF0,
    const float* __restrict__ bm0, bf16* __restrict__ h,
    bf16* __restrict__ msgF) {
  __shared__ float sW0[8*128];
  __shared__ float sb0[128];
  __shared__ bf16 h0s[128*128];   // swizzled; reused for h-tile later
  __shared__ bf16 sWT[128*128];   // swizzled W1^T
  const int t = threadIdx.x;
  const int w = t >> 6, lane = t & 63, l15 = lane & 15, g = lane >> 4;
  const int row_blk = blockIdx.x*128;
  for (int q = w; q < 32; q += 4)
    glds16((const char*)WTe + q*1024 + lane*16, (char*)(void*)sWT + q*1024);
  for (int i = t; i < 8*128; i += 256) sW0[i] = W0[i];
  if (t < 128) sb0[t] = b0[t];
  __syncthreads();
  // layer 1: thread owns 1 row, 64 cols
  {
    const int row = t & 127, colbase = (t >> 7) * 64;
    const float4* jp = (const float4*)(jets + ((size_t)row_blk + row)*8);
    float4 x0 = jp[0], x1 = jp[1];
    float x[8] = {x0.x,x0.y,x0.z,x0.w,x1.x,x1.y,x1.z,x1.w};
    const int sw = (row & 7) << 3;
#pragma unroll
    for (int cg = 0; cg < 16; ++cg) {
      int c0 = colbase + cg*4;
      bf16x4 o;
#pragma unroll
      for (int j = 0; j < 4; ++j) {
        float a = sb0[c0+j];
#pragma unroll
        for (int f = 0; f < 8; ++f) a = fmaf(x[f], sW0[f*128 + c0 + j], a);
        o[j] = (bf16)fmaxf(a, 0.f);
      }
      *(bf16x4*)(h0s + row*128 + (c0 ^ sw)) = o;
    }
  }
  __syncthreads();
  // layer 2: MFMA, 4 waves 2x2
  const int wr = (w & 1)*64, wc = (w >> 1)*64;
  f32x4 acc[4][4];
#pragma unroll
  for (int m = 0; m < 4; ++m)
#pragma unroll
    for (int n = 0; n < 4; ++n) acc[m][n] = (f32x4){0.f,0.f,0.f,0.f};
#pragma unroll
  for (int kk = 0; kk < 128; kk += 32) {
    bf16x8 bfr[4], wfr[4];
#pragma unroll
    for (int n = 0; n < 4; ++n) {
      int row = wr + n*16 + l15;
      bfr[n] = *(const bf16x8*)(h0s + row*128 + ((kk + 8*g) ^ ((row & 7) << 3)));
    }
#pragma unroll
    for (int m = 0; m < 4; ++m) {
      int c = wc + m*16 + l15;
      wfr[m] = *(const bf16x8*)(sWT + c*128 + ((kk + 8*g) ^ ((c & 7) << 3)));
    }
#pragma unroll
    for (int m = 0; m < 4; ++m)
#pragma unroll
      for (int n = 0; n < 4; ++n)
        acc[m][n] = __builtin_amdgcn_mfma_f32_16x16x32_bf16(wfr[m], bfr[n], acc[m][n], 0,0,0);
  }
  __syncthreads();   // everyone done reading h0s before overwrite
#pragma unroll
  for (int m = 0; m < 4; ++m) {
    f32x4 bs = *(const f32x4*)(b1 + wc + m*16 + g*4);
#pragma unroll
    for (int n = 0; n < 4; ++n) {
      int lr = wr + n*16 + l15;
      int r = row_blk + lr;
      int c0 = wc + m*16 + g*4;
      bf16x4 o;
#pragma unroll
      for (int j = 0; j < 4; ++j) o[j] = (bf16)fmaxf(acc[m][n][j] + bs[j], 0.f);
      *(bf16x4*)(h + (size_t)r*128 + c0) = o;
      *(bf16x4*)(h0s + lr*128 + (c0 ^ ((lr & 7) << 3))) = o;
    }
  }
  __syncthreads();
  // msg0: relu(htile @ Wm0 + bm0) -> msgF fragment-linear blocks
  {
    f32x4 acc2[4][4];
#pragma unroll
    for (int m = 0; m < 4; ++m)
#pragma unroll
      for (int n = 0; n < 4; ++n) acc2[m][n] = (f32x4){0.f,0.f,0.f,0.f};
#pragma unroll
    for (int kk = 0; kk < 128; kk += 32) {
      bf16x8 bfr[4], wfr[4];
#pragma unroll
      for (int n = 0; n < 4; ++n) {
        int lr = wr + n*16 + l15;
        bfr[n] = *(const bf16x8*)(h0s + lr*128 + ((kk + 8*g) ^ ((lr & 7) << 3)));
      }
#pragma unroll
      for (int m = 0; m < 4; ++m) {
        int cblk = (wc >> 4) + m;
        wfr[m] = *(const bf16x8*)(WmF0 + (size_t)(cblk*4 + (kk >> 5))*512 + lane*8);
      }
#pragma unroll
      for (int m = 0; m < 4; ++m)
#pragma unroll
        for (int n = 0; n < 4; ++n)
          acc2[m][n] = __builtin_amdgcn_mfma_f32_16x16x32_bf16(bfr[n], wfr[m], acc2[m][n], 0,0,0);
    }
    const int b = row_blk >> 9;
    const int rbase = (row_blk & 511) + wr;
#pragma unroll
    for (int m = 0; m < 4; ++m) {
      int c = wc + m*16 + l15;
      int mblk = (wc >> 4) + m;
      float bc = bm0[c];
#pragma unroll
      for (int n = 0; n < 4; ++n) {
        int rl = rbase + n*16 + g*4;
        bf16x4 o;
#pragma unroll
        for (int j = 0; j < 4; ++j) o[j] = (bf16)fmaxf(acc2[m][n][j] + bc, 0.f);
        size_t off = (size_t)b*65536 + (size_t)((rl>>5)*8 + mblk)*512
                   + (((rl>>3)&3)*16 + l15)*8 + (rl&7);
        *(bf16x4*)(msgF + off) = o;
      }
    }
  }
}

// -------------------------------------------------- fused per-iteration kernel
// Phase A: pure GEMM on fragment-linear PF/msgF, EXPLICIT 2-deep double-buffer
// of the 10-load cluster. __launch_bounds__(256,1) releases the VGPR budget
// (LDS binds occupancy at 2 blocks/CU; VGPR up to 256/wave is free) so the
// prefetch buffers actually materialize.
// Phase B: h_new = relu([h|agg]@Wu+bu)*mask (in-place h); WuF coalesced.
// Phase C (DO_MSG): msgFout = relu(h_new@Wm+bm)^T (fragment-linear out).
template<bool DO_MSG>
__global__ __launch_bounds__(256, 1) void iter_fused(
    const bf16* __restrict__ PF, const float* __restrict__ rsum,
    const float* __restrict__ mask, const bf16* __restrict__ msgFin,
    bf16* __restrict__ h,
    const bf16* __restrict__ WuF, const float* __restrict__ bu,
    const bf16* __restrict__ WmF, const float* __restrict__ bm,
    bf16* __restrict__ msgFout) {
  __shared__ __align__(16) char smem[65536];
  bf16* htile = (bf16*)smem;                 // [128][128] 32KB
  bf16* aggs  = (bf16*)(smem + 32768);       // [128][128] 32KB
  const int t = threadIdx.x;
  const int b  = blockIdx.x & 127;
  const int ic = blockIdx.x >> 7;             // 0..3
  const int i0 = ic*128;
  const int w = t >> 6, lane = t & 63, l15 = lane & 15, g = lane >> 4;

  // ================= Phase A: agg rows i0 + w*32 .. +31 (pipelined pure GEMM)
  {
    const int i0w = i0 + w*32;
    float r_i[2];
#pragma unroll
    for (int r = 0; r < 2; ++r) r_i[r] = rsum[(size_t)b*Nn + i0w + r*16 + l15];
    f32x4 acc[2][8];
#pragma unroll
    for (int r = 0; r < 2; ++r)
#pragma unroll
      for (int m = 0; m < 8; ++m) acc[r][m] = (f32x4){0.f,0.f,0.f,0.f};
    const bf16* mBF = msgFin + (size_t)b*65536 + lane*8;
    const bf16* pBF = PF + ((size_t)b*32 + (i0w >> 4))*16*512 + lane*8;

    bf16x8 afrA[8], afrB[8], pfrA[2], pfrB[2];
    auto loadA = [&](int kt) {
#pragma unroll
      for (int m = 0; m < 8; ++m) afrA[m] = *(const bf16x8*)(mBF + (kt*8 + m)*512);
      pfrA[0] = *(const bf16x8*)(pBF + kt*512);
      pfrA[1] = *(const bf16x8*)(pBF + (16 + kt)*512);
    };
    auto loadB = [&](int kt) {
#pragma unroll
      for (int m = 0; m < 8; ++m) afrB[m] = *(const bf16x8*)(mBF + (kt*8 + m)*512);
      pfrB[0] = *(const bf16x8*)(pBF + kt*512);
      pfrB[1] = *(const bf16x8*)(pBF + (16 + kt)*512);
    };
    auto compute = [&](const bf16x8* afr, const bf16x8* pfr) {
#pragma unroll
      for (int m = 0; m < 8; ++m) {
        acc[0][m] = __builtin_amdgcn_mfma_f32_16x16x32_bf16(afr[m], pfr[0], acc[0][m], 0,0,0);
        acc[1][m] = __builtin_amdgcn_mfma_f32_16x16x32_bf16(afr[m], pfr[1], acc[1][m], 0,0,0);
      }
    };

    loadA(0);
#pragma unroll
    for (int kt = 0; kt < 16; kt += 2) {
      loadB(kt + 1);
      compute(afrA, pfrA);
      if (kt + 2 < 16) loadA(kt + 2);
      compute(afrB, pfrB);
    }
    // epilogue -> aggs LDS (swizzled), normalized by r_i
#pragma unroll
    for (int r = 0; r < 2; ++r) {
      int lr = w*32 + r*16 + l15;      // local row 0..127
#pragma unroll
      for (int m = 0; m < 8; ++m) {
        bf16x4 o;
#pragma unroll
        for (int j = 0; j < 4; ++j) o[j] = (bf16)(acc[r][m][j] * r_i[r]);
        int c0 = m*16 + g*4;
        *(bf16x4*)(aggs + lr*128 + (c0 ^ ((lr & 7) << 3))) = o;
      }
    }
  }
  __syncthreads();   // aggs visible to all waves

  // ================= Phase B: h_new = relu([h|agg] @ Wu + bu) * mask
  const int wr = (w & 1)*64, wc = (w >> 1)*64;
  const size_t growbase = (size_t)b*Nn + i0;
  {
    f32x4 acc[4][4];
#pragma unroll
    for (int m = 0; m < 4; ++m)
#pragma unroll
      for (int n = 0; n < 4; ++n) acc[m][n] = (f32x4){0.f,0.f,0.f,0.f};
#pragma unroll
    for (int kk = 0; kk < 256; kk += 32) {
      bf16x8 bfr[4];
      if (kk < 128) {
#pragma unroll
        for (int n = 0; n < 4; ++n)
          bfr[n] = *(const bf16x8*)(h + (growbase + wr + n*16 + l15)*128 + kk + 8*g);
      } else {
#pragma unroll
        for (int n = 0; n < 4; ++n) {
          int lr = wr + n*16 + l15;
          int kl = (kk - 128) + 8*g;
          bfr[n] = *(const bf16x8*)(aggs + lr*128 + (kl ^ ((lr & 7) << 3)));
        }
      }
      bf16x8 wfr[4];
#pragma unroll
      for (int m = 0; m < 4; ++m) {
        int cblk = (wc >> 4) + m;
        wfr[m] = *(const bf16x8*)(WuF + (size_t)(cblk*8 + (kk >> 5))*512 + lane*8);
      }
#pragma unroll
      for (int m = 0; m < 4; ++m)
#pragma unroll
        for (int n = 0; n < 4; ++n)
          acc[m][n] = __builtin_amdgcn_mfma_f32_16x16x32_bf16(wfr[m], bfr[n], acc[m][n], 0,0,0);
    }
    __syncthreads();  // all h reads (cross-wave cols) + aggs reads drained
#pragma unroll
    for (int m = 0; m < 4; ++m) {
      f32x4 bs = *(const f32x4*)(bu + wc + m*16 + g*4);
#pragma unroll
      for (int n = 0; n < 4; ++n) {
        int lr = wr + n*16 + l15;
        size_t r = growbase + lr;
        float mv = mask[r];
        bf16x4 o;
#pragma unroll
        for (int j = 0; j < 4; ++j)
          o[j] = (bf16)(fmaxf(acc[m][n][j] + bs[j], 0.f) * mv);
        int c0 = wc + m*16 + g*4;
        *(bf16x4*)(h + r*128 + c0) = o;
        if (DO_MSG)
          *(bf16x4*)(htile + lr*128 + (c0 ^ ((lr & 7) << 3))) = o;
      }
    }
  }
  if (!DO_MSG) return;
  __syncthreads();   // htile visible

  // ================= Phase C: msgFout = relu(h_new @ Wm + bm)^T (frag-linear)
  {
    f32x4 acc[4][4];
#pragma unroll
    for (int m = 0; m < 4; ++m)
#pragma unroll
      for (int n = 0; n < 4; ++n) acc[m][n] = (f32x4){0.f,0.f,0.f,0.f};
#pragma unroll
    for (int kk = 0; kk < 128; kk += 32) {
      bf16x8 bfr[4], wfr[4];
#pragma unroll
      for (int n = 0; n < 4; ++n) {
        int lr = wr + n*16 + l15;
        bfr[n] = *(const bf16x8*)(htile + lr*128 + ((kk + 8*g) ^ ((lr & 7) << 3)));
      }
#pragma unroll
      for (int m = 0; m < 4; ++m) {
        int cblk = (wc >> 4) + m;
        wfr[m] = *(const bf16x8*)(WmF + (size_t)(cblk*4 + (kk >> 5))*512 + lane*8);
      }
#pragma unroll
      for (int m = 0; m < 4; ++m)
#pragma unroll
        for (int n = 0; n < 4; ++n)
          acc[m][n] = __builtin_amdgcn_mfma_f32_16x16x32_bf16(bfr[n], wfr[m], acc[m][n], 0,0,0);
    }
#pragma unroll
    for (int m = 0; m < 4; ++m) {
      int c = wc + m*16 + l15;
      int mblk = (wc >> 4) + m;
      float bc = bm[c];
#pragma unroll
      for (int n = 0; n < 4; ++n) {
        int rl = i0 + wr + n*16 + g*4;
        bf16x4 o;
#pragma unroll
        for (int j = 0; j < 4; ++j) o[j] = (bf16)fmaxf(acc[m][n][j] + bc, 0.f);
        size_t off = (size_t)b*65536 + (size_t)((rl>>5)*8 + mblk)*512
                   + (((rl>>3)&3)*16 + l15)*8 + (rl&7);
        *(bf16x4*)(msgFout + off) = o;
      }
    }
  }
}

// -------------------------------------------------- fused pool + readout
__global__ __launch_bounds__(256) void pool_readout(
    const bf16* __restrict__ h, const float* __restrict__ mask,
    const float* __restrict__ W1, const float* __restrict__ b1,
    const float* __restrict__ W2, const float* __restrict__ b2,
    float* __restrict__ out) {
  __shared__ float part[3][128];
  __shared__ float pl[128];
  __shared__ float hid[128];
  int b = blockIdx.x, t = threadIdx.x, g = t >> 6, cp = (t & 63)*2;
  float a0 = 0.f, a1 = 0.f;
  for (int n = g*128; n < g*128+128; ++n) {
    float mv = mask[(size_t)b*Nn + n];
    bf16x2 v = *(const bf16x2*)(h + ((size_t)b*Nn + n)*128 + cp);
    a0 = fmaf((float)v[0], mv, a0);
    a1 = fmaf((float)v[1], mv, a1);
  }
  if (g > 0) { part[g-1][cp] = a0; part[g-1][cp+1] = a1; }
  __syncthreads();
  if (g == 0) {
    pl[cp]   = a0 + part[0][cp]   + part[1][cp]   + part[2][cp];
    pl[cp+1] = a1 + part[0][cp+1] + part[1][cp+1] + part[2][cp+1];
  }
  __syncthreads();
  if (t < 128) {
    float a = b1[t];
#pragma unroll 4
    for (int j = 0; j < 128; ++j) a = fmaf(pl[j], W1[j*128 + t], a);
    hid[t] = fmaxf(a, 0.f);
  }
  __syncthreads();
  if (t < 128) {
    float a = b2[t];
#pragma unroll 4
    for (int j = 0; j < 128; ++j) a = fmaf(hid[j], W2[j*128 + t], a);
    out[(size_t)b*128 + t] = a;
  }
}

// -------------------------------------------------- launch
extern "C" void kernel_launch(void* const* d_in, const int* in_sizes, int n_in,
                              void* d_out, int out_size, void* d_ws, size_t ws_size,
                              hipStream_t stream) {
  const float* jets = (const float*)d_in[0];
  const float* mask = (const float*)d_in[1];
  const float* eW0  = (const float*)d_in[2];
  const float* eb0  = (const float*)d_in[3];
  const float* eW1  = (const float*)d_in[4];
  const float* eb1  = (const float*)d_in[5];
  const float* Wm   = (const float*)d_in[6];
  const float* bm   = (const float*)d_in[7];
  const float* Wu   = (const float*)d_in[8];
  const float* bu   = (const float*)d_in[9];
  const float* rW1  = (const float*)d_in[10];
  const float* rb1  = (const float*)d_in[11];
  const float* rW2  = (const float*)d_in[12];
  const float* rb2  = (const float*)d_in[13];
  float* out = (float*)d_out;

  bf16* h     = (bf16*)d_ws;                    // ROWS*128
  bf16* msgFA = h     + (size_t)ROWS*128;       // ROWS*128 (fragment-linear)
  bf16* msgFB = msgFA + (size_t)ROWS*128;       // ROWS*128 (ping-pong)
  bf16* PF    = msgFB + (size_t)ROWS*128;       // Bb*512*512 (67 MB, frag-linear E)
  bf16* WTe   = PF    + (size_t)Bb*512*512;     // 128*128 (old layout)
  bf16* WmF   = WTe   + 128*128;                // 3*128*128 (frag-linear)
  bf16* WuF   = WmF   + 3*128*128;              // 3*256*128 (frag-linear)
  float* rsum = (float*)(WuF + 3*256*128);      // ROWS (1/l_i)

  prep_pmat<<<512 + 640, 256, 0, stream>>>(eW1, Wm, Wu, WTe, WmF, WuF,
                                           jets, mask, PF, rsum);
  embed_msg0<<<ROWS/128, 256, 0, stream>>>(jets, eW0, eb0, WTe, eb1,
                                           WmF, bm, h, msgFA);
  // iter 0: msgFA -> msgFB
  iter_fused<true><<<Bb*4, 256, 0, stream>>>(
      PF, rsum, mask, msgFA, h,
      WuF, bu, WmF + (size_t)1*128*128, bm + 1*128, msgFB);
  // iter 1: msgFB -> msgFA
  iter_fused<true><<<Bb*4, 256, 0, stream>>>(
      PF, rsum, mask, msgFB, h,
      WuF + (size_t)1*256*128, bu + 1*128,
      WmF + (size_t)2*128*128, bm + 2*128, msgFA);
  // iter 2 (no next msg): reads msgFA
  iter_fused<false><<<Bb*4, 256, 0, stream>>>(
      PF, rsum, mask, msgFA, h,
      WuF + (size_t)2*256*128, bu + 2*128, nullptr, nullptr, nullptr);

  pool_readout<<<Bb, 256, 0, stream>>>(h, mask, rW1, rb1, rW2, rb2, out);
}

// Round 19
// 158.674 us; speedup vs baseline: 1.0583x; 1.0029x over previous
//
#include <hip/hip_runtime.h>
#include <stdint.h>
#include <stddef.h>

#define Bb 128
#define Nn 512
#define Hh 128
#define ROWS (Bb*Nn)

typedef __bf16 bf16;
typedef __bf16 bf16x2 __attribute__((ext_vector_type(2)));
typedef __bf16 bf16x4 __attribute__((ext_vector_type(4)));
typedef __bf16 bf16x8 __attribute__((ext_vector_type(8)));
typedef float  f32x4  __attribute__((ext_vector_type(4)));

__device__ __forceinline__ void glds16(const void* g, void* l) {
  __builtin_amdgcn_global_load_lds(
      (const __attribute__((address_space(1))) void*)g,
      (__attribute__((address_space(3))) void*)l, 16, 0, 0);
}

// ============================ fragment-linear layouts ============================
// A 16(row)x32(k) bf16 MFMA subtile is stored as ONE 1KB block in lane order:
// lane l = g*16+l15 holds elements (row=l15, k=8g..8g+7) at block + l*16B.
// msgF[b]: block index kt*8 + mblk           (kt=j/32, mblk=channel/16)
// PF[b]:   block index it*16 + kt            (it=i/16,  kt=j/32)
// WuF[s]:  block index cblk*8 + kt (K=256)   WmF[s]: cblk*4 + kt (K=128)
// Consumers load block + lane*8 elements -> 64 lanes read contiguous 1KB.

// -------------------------------------------------- prep + pmat (one dispatch)
__global__ __launch_bounds__(256) void prep_pmat(
    const float* __restrict__ eW1, const float* __restrict__ Wm,
    const float* __restrict__ Wu, bf16* __restrict__ WTe,
    bf16* __restrict__ WmF, bf16* __restrict__ WuF,
    const float* __restrict__ jets, const float* __restrict__ mask,
    bf16* __restrict__ PF, float* __restrict__ rsum) {
  __shared__ float Xs[Nn*9];
  __shared__ float cbs[Nn];
  const int t = threadIdx.x;
  if (blockIdx.x >= 512) {               // ---- weight prep half
    int idx = (blockIdx.x - 512)*256 + t;
    if (idx < 16384) {                       // eW1: 128x128 (swizzled, LDS path)
      int k = idx >> 7, c = idx & 127;
      WTe[c*128 + (k ^ ((c & 7) << 3))] = (bf16)eW1[idx];
    } else if (idx < 65536) {                // Wm: 3x128x128 -> fragment-linear
      int sub = idx - 16384;
      int s = sub >> 14, r = sub & 16383;
      int k = r >> 7, c = r & 127;
      WmF[s*16384 + (((c>>4)*4 + (k>>5))*64 + ((k>>3)&3)*16 + (c&15))*8 + (k&7)] = (bf16)Wm[sub];
    } else {                                 // Wu: 3x256x128 -> fragment-linear
      int sub = idx - 65536;
      int s = sub >> 15, r = sub & 32767;
      int k = r >> 7, c = r & 127;
      WuF[s*32768 + (((c>>4)*8 + (k>>5))*64 + ((k>>3)&3)*16 + (c&15))*8 + (k&7)] = (bf16)Wu[sub];
    }
    return;
  }
  // ---- pmat half (b = wgid&127 keeps XCD mapping identical to iter_fused)
  const int b = blockIdx.x & 127, ic = blockIdx.x >> 7;
  const int i0 = ic*128;
  const float* jb = jets + (size_t)b*Nn*8;
  for (int j = t; j < Nn; j += 256) {
    float s2 = 0.f;
#pragma unroll
    for (int f = 0; f < 8; ++f) { float v = jb[j*8+f]; Xs[j*9+f] = v; s2 = fmaf(v,v,s2); }
    cbs[j] = s2 + (mask[(size_t)b*Nn+j] > 0.f ? 0.f : 1e9f);
  }
  __syncthreads();
  const int w = t >> 6, lane = t & 63, l15 = lane & 15, g = lane >> 4;
  const int i0w = i0 + w*32;
  float xi2[2][8], sqi[2], lsum[2];
#pragma unroll
  for (int r = 0; r < 2; ++r) {
    int i = i0w + r*16 + l15;
    float sq = 0.f;
#pragma unroll
    for (int f = 0; f < 8; ++f) {
      float v = Xs[i*9+f];
      xi2[r][f] = 2.f*v;
      sq = fmaf(v, v, sq);
    }
    sqi[r] = sq;
    lsum[r] = 0.f;
  }
  bf16* Pr[2];
#pragma unroll
  for (int r = 0; r < 2; ++r) {
    int it = (i0w >> 4) + r;
    Pr[r] = PF + (((size_t)b*32 + it)*16)*512 + lane*8;
  }
#pragma unroll 2
  for (int j0 = 0; j0 < Nn; j0 += 32) {
    bf16x8 pfr[2];
#pragma unroll
    for (int e = 0; e < 8; ++e) {
      int j = j0 + 8*g + e;
      float xj[8];
#pragma unroll
      for (int f = 0; f < 8; ++f) xj[f] = Xs[j*9+f];
      float cb = cbs[j];
      float d0 = -(cb + sqi[0]);
      float d1 = -(cb + sqi[1]);
#pragma unroll
      for (int f = 0; f < 8; ++f) {
        d0 = fmaf(xi2[0][f], xj[f], d0);
        d1 = fmaf(xi2[1][f], xj[f], d1);
      }
      float ev0 = __expf(d0), ev1 = __expf(d1);
      lsum[0] += ev0; lsum[1] += ev1;
      pfr[0][e] = (bf16)ev0;
      pfr[1][e] = (bf16)ev1;
    }
#pragma unroll
    for (int r = 0; r < 2; ++r)
      *(bf16x8*)(Pr[r] + (j0 >> 5)*512) = pfr[r];
  }
#pragma unroll
  for (int r = 0; r < 2; ++r) {
    float s = lsum[r];
    s += __shfl_xor(s, 16, 64);
    s += __shfl_xor(s, 32, 64);
    if (g == 0) rsum[(size_t)b*Nn + i0w + r*16 + l15] = 1.f/s;
  }
}

// -------------------------------------------------- fused embed L1+L2+msg0
__global__ __launch_bounds__(256) void embed_msg0(
    const float* __restrict__ jets, const float* __restrict__ W0,
    const float* __restrict__ b0, const bf16* __restrict__ WTe,
    const float* __restrict__ b1, const bf16* __restrict__ WmF0,
    const float* __restrict__ bm0, bf16* __restrict__ h,
    bf16* __restrict__ msgF) {
  __shared__ float sW0[8*128];
  __shared__ float sb0[128];
  __shared__ bf16 h0s[128*128];   // swizzled; reused for h-tile later
  __shared__ bf16 sWT[128*128];   // swizzled W1^T
  const int t = threadIdx.x;
  const int w = t >> 6, lane = t & 63, l15 = lane & 15, g = lane >> 4;
  const int row_blk = blockIdx.x*128;
  for (int q = w; q < 32; q += 4)
    glds16((const char*)WTe + q*1024 + lane*16, (char*)(void*)sWT + q*1024);
  for (int i = t; i < 8*128; i += 256) sW0[i] = W0[i];
  if (t < 128) sb0[t] = b0[t];
  __syncthreads();
  // layer 1: thread owns 1 row, 64 cols
  {
    const int row = t & 127, colbase = (t >> 7) * 64;
    const float4* jp = (const float4*)(jets + ((size_t)row_blk + row)*8);
    float4 x0 = jp[0], x1 = jp[1];
    float x[8] = {x0.x,x0.y,x0.z,x0.w,x1.x,x1.y,x1.z,x1.w};
    const int sw = (row & 7) << 3;
#pragma unroll
    for (int cg = 0; cg < 16; ++cg) {
      int c0 = colbase + cg*4;
      bf16x4 o;
#pragma unroll
      for (int j = 0; j < 4; ++j) {
        float a = sb0[c0+j];
#pragma unroll
        for (int f = 0; f < 8; ++f) a = fmaf(x[f], sW0[f*128 + c0 + j], a);
        o[j] = (bf16)fmaxf(a, 0.f);
      }
      *(bf16x4*)(h0s + row*128 + (c0 ^ sw)) = o;
    }
  }
  __syncthreads();
  // layer 2: MFMA, 4 waves 2x2
  const int wr = (w & 1)*64, wc = (w >> 1)*64;
  f32x4 acc[4][4];
#pragma unroll
  for (int m = 0; m < 4; ++m)
#pragma unroll
    for (int n = 0; n < 4; ++n) acc[m][n] = (f32x4){0.f,0.f,0.f,0.f};
#pragma unroll
  for (int kk = 0; kk < 128; kk += 32) {
    bf16x8 bfr[4], wfr[4];
#pragma unroll
    for (int n = 0; n < 4; ++n) {
      int row = wr + n*16 + l15;
      bfr[n] = *(const bf16x8*)(h0s + row*128 + ((kk + 8*g) ^ ((row & 7) << 3)));
    }
#pragma unroll
    for (int m = 0; m < 4; ++m) {
      int c = wc + m*16 + l15;
      wfr[m] = *(const bf16x8*)(sWT + c*128 + ((kk + 8*g) ^ ((c & 7) << 3)));
    }
#pragma unroll
    for (int m = 0; m < 4; ++m)
#pragma unroll
      for (int n = 0; n < 4; ++n)
        acc[m][n] = __builtin_amdgcn_mfma_f32_16x16x32_bf16(wfr[m], bfr[n], acc[m][n], 0,0,0);
  }
  __syncthreads();   // everyone done reading h0s before overwrite
#pragma unroll
  for (int m = 0; m < 4; ++m) {
    f32x4 bs = *(const f32x4*)(b1 + wc + m*16 + g*4);
#pragma unroll
    for (int n = 0; n < 4; ++n) {
      int lr = wr + n*16 + l15;
      int r = row_blk + lr;
      int c0 = wc + m*16 + g*4;
      bf16x4 o;
#pragma unroll
      for (int j = 0; j < 4; ++j) o[j] = (bf16)fmaxf(acc[m][n][j] + bs[j], 0.f);
      *(bf16x4*)(h + (size_t)r*128 + c0) = o;
      *(bf16x4*)(h0s + lr*128 + (c0 ^ ((lr & 7) << 3))) = o;
    }
  }
  __syncthreads();
  // msg0: relu(htile @ Wm0 + bm0) -> msgF fragment-linear blocks
  {
    f32x4 acc2[4][4];
#pragma unroll
    for (int m = 0; m < 4; ++m)
#pragma unroll
      for (int n = 0; n < 4; ++n) acc2[m][n] = (f32x4){0.f,0.f,0.f,0.f};
#pragma unroll
    for (int kk = 0; kk < 128; kk += 32) {
      bf16x8 bfr[4], wfr[4];
#pragma unroll
      for (int n = 0; n < 4; ++n) {
        int lr = wr + n*16 + l15;
        bfr[n] = *(const bf16x8*)(h0s + lr*128 + ((kk + 8*g) ^ ((lr & 7) << 3)));
      }
#pragma unroll
      for (int m = 0; m < 4; ++m) {
        int cblk = (wc >> 4) + m;
        wfr[m] = *(const bf16x8*)(WmF0 + (size_t)(cblk*4 + (kk >> 5))*512 + lane*8);
      }
#pragma unroll
      for (int m = 0; m < 4; ++m)
#pragma unroll
        for (int n = 0; n < 4; ++n)
          acc2[m][n] = __builtin_amdgcn_mfma_f32_16x16x32_bf16(bfr[n], wfr[m], acc2[m][n], 0,0,0);
    }
    const int b = row_blk >> 9;
    const int rbase = (row_blk & 511) + wr;
#pragma unroll
    for (int m = 0; m < 4; ++m) {
      int c = wc + m*16 + l15;
      int mblk = (wc >> 4) + m;
      float bc = bm0[c];
#pragma unroll
      for (int n = 0; n < 4; ++n) {
        int rl = rbase + n*16 + g*4;
        bf16x4 o;
#pragma unroll
        for (int j = 0; j < 4; ++j) o[j] = (bf16)fmaxf(acc2[m][n][j] + bc, 0.f);
        size_t off = (size_t)b*65536 + (size_t)((rl>>5)*8 + mblk)*512
                   + (((rl>>3)&3)*16 + l15)*8 + (rl&7);
        *(bf16x4*)(msgF + off) = o;
      }
    }
  }
}

// -------------------------------------------------- fused per-iteration kernel
// Phase A: msgF (wave-invariant!) staged into LDS via global_load_lds,
// double-buffered in 32KB halves (4x less L2 traffic, async queue); all 4
// waves ds_read_b128 the shared copy (contiguous, conflict-free). PF stays
// per-wave global, 8 loads batched per quarter. aggs overwrites half 1 only
// after the barrier ending all afr reads. __launch_bounds__(256,1) keeps the
// register budget open (LDS binds occupancy at 2 blocks/CU anyway).
// Phase B: h_new = relu([h|agg]@Wu+bu)*mask (in-place h); WuF coalesced.
// Phase C (DO_MSG): msgFout = relu(h_new@Wm+bm)^T (fragment-linear out).
template<bool DO_MSG>
__global__ __launch_bounds__(256, 1) void iter_fused(
    const bf16* __restrict__ PF, const float* __restrict__ rsum,
    const float* __restrict__ mask, const bf16* __restrict__ msgFin,
    bf16* __restrict__ h,
    const bf16* __restrict__ WuF, const float* __restrict__ bu,
    const bf16* __restrict__ WmF, const float* __restrict__ bm,
    bf16* __restrict__ msgFout) {
  __shared__ __align__(16) char smem[65536];
  bf16* htile = (bf16*)smem;                 // [128][128] 32KB (phase B/C)
  bf16* aggs  = (bf16*)(smem + 32768);       // [128][128] 32KB (phase A epi+)
  const int t = threadIdx.x;
  const int b  = blockIdx.x & 127;
  const int ic = blockIdx.x >> 7;             // 0..3
  const int i0 = ic*128;
  const int w = t >> 6, lane = t & 63, l15 = lane & 15, g = lane >> 4;

  // ================= Phase A: agg rows i0 + w*32 .. +31
  {
    const int i0w = i0 + w*32;
    float r_i[2];
#pragma unroll
    for (int r = 0; r < 2; ++r) r_i[r] = rsum[(size_t)b*Nn + i0w + r*16 + l15];
    f32x4 acc[2][8];
#pragma unroll
    for (int r = 0; r < 2; ++r)
#pragma unroll
      for (int m = 0; m < 8; ++m) acc[r][m] = (f32x4){0.f,0.f,0.f,0.f};
    const char* mSrc = (const char*)(msgFin + (size_t)b*65536);  // 128KB slice
    const bf16* pBF  = PF + ((size_t)b*32 + (i0w >> 4))*16*512 + lane*8;

    // stage 32 blocks (4 kt) into LDS half (0 or 1); 8 glds16 per wave
    auto stage = [&](int ktBase, int half) {
      const char* src = mSrc + ktBase*8192;
      char* dst = (char*)smem + half*32768;
      for (int q = w; q < 32; q += 4)
        glds16(src + q*1024 + lane*16, dst + q*1024);
    };
    // compute 4 kt from LDS half; PF fragments batched 8-deep
    auto computeQ = [&](int ktBase, int half) {
      const bf16* sbase = (const bf16*)((const char*)smem + half*32768);
      bf16x8 pq[8];
#pragma unroll
      for (int k2 = 0; k2 < 4; ++k2) {
        pq[k2*2]   = *(const bf16x8*)(pBF + (ktBase + k2)*512);
        pq[k2*2+1] = *(const bf16x8*)(pBF + (16 + ktBase + k2)*512);
      }
#pragma unroll
      for (int k2 = 0; k2 < 4; ++k2) {
        bf16x8 afr[8];
#pragma unroll
        for (int m = 0; m < 8; ++m)
          afr[m] = *(const bf16x8*)(sbase + (k2*8 + m)*512 + lane*8);
#pragma unroll
        for (int m = 0; m < 8; ++m) {
          acc[0][m] = __builtin_amdgcn_mfma_f32_16x16x32_bf16(afr[m], pq[k2*2],   acc[0][m], 0,0,0);
          acc[1][m] = __builtin_amdgcn_mfma_f32_16x16x32_bf16(afr[m], pq[k2*2+1], acc[1][m], 0,0,0);
        }
      }
    };

    stage(0, 0);
    __syncthreads();
    stage(4, 1);  computeQ(0, 0);
    __syncthreads();
    stage(8, 0);  computeQ(4, 1);
    __syncthreads();
    stage(12, 1); computeQ(8, 0);
    __syncthreads();
    computeQ(12, 1);
    __syncthreads();   // all afr reads of half 1 done -> aggs may overwrite it

    // epilogue -> aggs LDS (swizzled), normalized by r_i
#pragma unroll
    for (int r = 0; r < 2; ++r) {
      int lr = w*32 + r*16 + l15;      // local row 0..127
#pragma unroll
      for (int m = 0; m < 8; ++m) {
        bf16x4 o;
#pragma unroll
        for (int j = 0; j < 4; ++j) o[j] = (bf16)(acc[r][m][j] * r_i[r]);
        int c0 = m*16 + g*4;
        *(bf16x4*)(aggs + lr*128 + (c0 ^ ((lr & 7) << 3))) = o;
      }
    }
  }
  __syncthreads();   // aggs visible to all waves

  // ================= Phase B: h_new = relu([h|agg] @ Wu + bu) * mask
  const int wr = (w & 1)*64, wc = (w >> 1)*64;
  const size_t growbase = (size_t)b*Nn + i0;
  {
    f32x4 acc[4][4];
#pragma unroll
    for (int m = 0; m < 4; ++m)
#pragma unroll
      for (int n = 0; n < 4; ++n) acc[m][n] = (f32x4){0.f,0.f,0.f,0.f};
#pragma unroll
    for (int kk = 0; kk < 256; kk += 32) {
      bf16x8 bfr[4];
      if (kk < 128) {
#pragma unroll
        for (int n = 0; n < 4; ++n)
          bfr[n] = *(const bf16x8*)(h + (growbase + wr + n*16 + l15)*128 + kk + 8*g);
      } else {
#pragma unroll
        for (int n = 0; n < 4; ++n) {
          int lr = wr + n*16 + l15;
          int kl = (kk - 128) + 8*g;
          bfr[n] = *(const bf16x8*)(aggs + lr*128 + (kl ^ ((lr & 7) << 3)));
        }
      }
      bf16x8 wfr[4];
#pragma unroll
      for (int m = 0; m < 4; ++m) {
        int cblk = (wc >> 4) + m;
        wfr[m] = *(const bf16x8*)(WuF + (size_t)(cblk*8 + (kk >> 5))*512 + lane*8);
      }
#pragma unroll
      for (int m = 0; m < 4; ++m)
#pragma unroll
        for (int n = 0; n < 4; ++n)
          acc[m][n] = __builtin_amdgcn_mfma_f32_16x16x32_bf16(wfr[m], bfr[n], acc[m][n], 0,0,0);
    }
    __syncthreads();  // all h reads (cross-wave cols) + aggs reads drained
#pragma unroll
    for (int m = 0; m < 4; ++m) {
      f32x4 bs = *(const f32x4*)(bu + wc + m*16 + g*4);
#pragma unroll
      for (int n = 0; n < 4; ++n) {
        int lr = wr + n*16 + l15;
        size_t r = growbase + lr;
        float mv = mask[r];
        bf16x4 o;
#pragma unroll
        for (int j = 0; j < 4; ++j)
          o[j] = (bf16)(fmaxf(acc[m][n][j] + bs[j], 0.f) * mv);
        int c0 = wc + m*16 + g*4;
        *(bf16x4*)(h + r*128 + c0) = o;
        if (DO_MSG)
          *(bf16x4*)(htile + lr*128 + (c0 ^ ((lr & 7) << 3))) = o;
      }
    }
  }
  if (!DO_MSG) return;
  __syncthreads();   // htile visible

  // ================= Phase C: msgFout = relu(h_new @ Wm + bm)^T (frag-linear)
  {
    f32x4 acc[4][4];
#pragma unroll
    for (int m = 0; m < 4; ++m)
#pragma unroll
      for (int n = 0; n < 4; ++n) acc[m][n] = (f32x4){0.f,0.f,0.f,0.f};
#pragma unroll
    for (int kk = 0; kk < 128; kk += 32) {
      bf16x8 bfr[4], wfr[4];
#pragma unroll
      for (int n = 0; n < 4; ++n) {
        int lr = wr + n*16 + l15;
        bfr[n] = *(const bf16x8*)(htile + lr*128 + ((kk + 8*g) ^ ((lr & 7) << 3)));
      }
#pragma unroll
      for (int m = 0; m < 4; ++m) {
        int cblk = (wc >> 4) + m;
        wfr[m] = *(const bf16x8*)(WmF + (size_t)(cblk*4 + (kk >> 5))*512 + lane*8);
      }
#pragma unroll
      for (int m = 0; m < 4; ++m)
#pragma unroll
        for (int n = 0; n < 4; ++n)
          acc[m][n] = __builtin_amdgcn_mfma_f32_16x16x32_bf16(bfr[n], wfr[m], acc[m][n], 0,0,0);
    }
#pragma unroll
    for (int m = 0; m < 4; ++m) {
      int c = wc + m*16 + l15;
      int mblk = (wc >> 4) + m;
      float bc = bm[c];
#pragma unroll
      for (int n = 0; n < 4; ++n) {
        int rl = i0 + wr + n*16 + g*4;
        bf16x4 o;
#pragma unroll
        for (int j = 0; j < 4; ++j) o[j] = (bf16)fmaxf(acc[m][n][j] + bc, 0.f);
        size_t off = (size_t)b*65536 + (size_t)((rl>>5)*8 + mblk)*512
                   + (((rl>>3)&3)*16 + l15)*8 + (rl&7);
        *(bf16x4*)(msgFout + off) = o;
      }
    }
  }
}

// -------------------------------------------------- fused pool + readout
__global__ __launch_bounds__(256) void pool_readout(
    const bf16* __restrict__ h, const float* __restrict__ mask,
    const float* __restrict__ W1, const float* __restrict__ b1,
    const float* __restrict__ W2, const float* __restrict__ b2,
    float* __restrict__ out) {
  __shared__ float part[3][128];
  __shared__ float pl[128];
  __shared__ float hid[128];
  int b = blockIdx.x, t = threadIdx.x, g = t >> 6, cp = (t & 63)*2;
  float a0 = 0.f, a1 = 0.f;
  for (int n = g*128; n < g*128+128; ++n) {
    float mv = mask[(size_t)b*Nn + n];
    bf16x2 v = *(const bf16x2*)(h + ((size_t)b*Nn + n)*128 + cp);
    a0 = fmaf((float)v[0], mv, a0);
    a1 = fmaf((float)v[1], mv, a1);
  }
  if (g > 0) { part[g-1][cp] = a0; part[g-1][cp+1] = a1; }
  __syncthreads();
  if (g == 0) {
    pl[cp]   = a0 + part[0][cp]   + part[1][cp]   + part[2][cp];
    pl[cp+1] = a1 + part[0][cp+1] + part[1][cp+1] + part[2][cp+1];
  }
  __syncthreads();
  if (t < 128) {
    float a = b1[t];
#pragma unroll 4
    for (int j = 0; j < 128; ++j) a = fmaf(pl[j], W1[j*128 + t], a);
    hid[t] = fmaxf(a, 0.f);
  }
  __syncthreads();
  if (t < 128) {
    float a = b2[t];
#pragma unroll 4
    for (int j = 0; j < 128; ++j) a = fmaf(hid[j], W2[j*128 + t], a);
    out[(size_t)b*128 + t] = a;
  }
}

// -------------------------------------------------- launch
extern "C" void kernel_launch(void* const* d_in, const int* in_sizes, int n_in,
                              void* d_out, int out_size, void* d_ws, size_t ws_size,
                              hipStream_t stream) {
  const float* jets = (const float*)d_in[0];
  const float* mask = (const float*)d_in[1];
  const float* eW0  = (const float*)d_in[2];
  const float* eb0  = (const float*)d_in[3];
  const float* eW1  = (const float*)d_in[4];
  const float* eb1  = (const float*)d_in[5];
  const float* Wm   = (const float*)d_in[6];
  const float* bm   = (const float*)d_in[7];
  const float* Wu   = (const float*)d_in[8];
  const float* bu   = (const float*)d_in[9];
  const float* rW1  = (const float*)d_in[10];
  const float* rb1  = (const float*)d_in[11];
  const float* rW2  = (const float*)d_in[12];
  const float* rb2  = (const float*)d_in[13];
  float* out = (float*)d_out;

  bf16* h     = (bf16*)d_ws;                    // ROWS*128
  bf16* msgFA = h     + (size_t)ROWS*128;       // ROWS*128 (fragment-linear)
  bf16* msgFB = msgFA + (size_t)ROWS*128;       // ROWS*128 (ping-pong)
  bf16* PF    = msgFB + (size_t)ROWS*128;       // Bb*512*512 (67 MB, frag-linear E)
  bf16* WTe   = PF    + (size_t)Bb*512*512;     // 128*128 (old layout)
  bf16* WmF   = WTe   + 128*128;                // 3*128*128 (frag-linear)
  bf16* WuF   = WmF   + 3*128*128;              // 3*256*128 (frag-linear)
  float* rsum = (float*)(WuF + 3*256*128);      // ROWS (1/l_i)

  prep_pmat<<<512 + 640, 256, 0, stream>>>(eW1, Wm, Wu, WTe, WmF, WuF,
                                           jets, mask, PF, rsum);
  embed_msg0<<<ROWS/128, 256, 0, stream>>>(jets, eW0, eb0, WTe, eb1,
                                           WmF, bm, h, msgFA);
  // iter 0: msgFA -> msgFB
  iter_fused<true><<<Bb*4, 256, 0, stream>>>(
      PF, rsum, mask, msgFA, h,
      WuF, bu, WmF + (size_t)1*128*128, bm + 1*128, msgFB);
  // iter 1: msgFB -> msgFA
  iter_fused<true><<<Bb*4, 256, 0, stream>>>(
      PF, rsum, mask, msgFB, h,
      WuF + (size_t)1*256*128, bu + 1*128,
      WmF + (size_t)2*128*128, bm + 2*128, msgFA);
  // iter 2 (no next msg): reads msgFA
  iter_fused<false><<<Bb*4, 256, 0, stream>>>(
      PF, rsum, mask, msgFA, h,
      WuF + (size_t)2*256*128, bu + 2*128, nullptr, nullptr, nullptr);

  pool_readout<<<Bb, 256, 0, stream>>>(h, mask, rW1, rb1, rW2, rb2, out);
}